// Round 8
// baseline (1266.168 us; speedup 1.0000x reference)
//
#include <hip/hip_runtime.h>
#include <stdint.h>

typedef uint16_t u16;
typedef __attribute__((ext_vector_type(8))) short    bf16x8;  // 8 bf16 (4 VGPRs)
typedef __attribute__((ext_vector_type(8))) uint16_t u16x8;
typedef __attribute__((ext_vector_type(4))) float    f32x4;

#define B_    2
#define N_    100000
#define K_    26
#define CIN_  32
#define COUT_ 32
#define MID_  50000                                   // node-range split point

#define XT_ROWS  (N_ + 1)
#define XT_BYTES ((size_t)B_ * XT_ROWS * CIN_ * 2)   // 12,800,128 bytes

// ---- prep kernel geometry (R3 structure: xt [B][N+1][32] bf16, Wb [32][832]) ----
#define TCHUNK      64
#define TBLK_PER_B  ((N_ + TCHUNK - 1) / TCHUNK)     // 1563
#define TBLKS       (B_ * TBLK_PER_B)                // 3126
#define WBLKS       13                               // 13 * 2048 = 26624 W elems
#define PREP_GRID   (TBLKS + 1 + WBLKS)

// ---- conv kernel geometry ----
// Grid = 1024 blocks = 4 blocks/CU x 256 CU -> ENTIRE grid co-resident at t=0
// (VGPR<=128 via launch_bounds, LDS 28.7KB). Batch b = (bid&7)>>2 -> XCD half.
// Per batch: 512 blocks x 4 waves = 2048 waves; 6250 tiles -> <=4 tiles/wave.
#define CONV_GRID   1024
#define WPB         2048                             // waves per batch
#define TILES_PB    (N_ / 16)                        // 6250 exact

__device__ __forceinline__ u16 f2bf(float f) {
    union { float f; uint32_t u; } v; v.f = f;
    return (u16)((v.u + 0x7FFFu + ((v.u >> 16) & 1u)) >> 16);  // RNE
}

// Transpose inp [B][CIN][N] f32 -> xt [B][N+1][CIN] bf16 (64B rows),
// fill row at n==N, W -> Wb [32][832] bf16.
__global__ __launch_bounds__(256) void prep_kernel(
    const float* __restrict__ inp, const float* __restrict__ W,
    const float* __restrict__ fill, u16* __restrict__ xt, u16* __restrict__ Wb)
{
    int tid = threadIdx.x;
    int blk = blockIdx.x;
    if (blk >= TBLKS) {
        int job = blk - TBLKS;
        if (job == 0) {
            if (tid < B_ * CIN_) {
                int b = tid >> 5, c = tid & 31;
                xt[((size_t)b * XT_ROWS + N_) * CIN_ + c] = f2bf(fill[c]);
            }
        } else {
            int base = (job - 1) * 2048 + tid * 8;   // exact: 13*2048 = 26624
            const float4* src = (const float4*)(W + base);
            float4 x = src[0], y = src[1];
            u16x8 o;
            o[0] = f2bf(x.x); o[1] = f2bf(x.y); o[2] = f2bf(x.z); o[3] = f2bf(x.w);
            o[4] = f2bf(y.x); o[5] = f2bf(y.y); o[6] = f2bf(y.z); o[7] = f2bf(y.w);
            *(u16x8*)(Wb + base) = o;
        }
        return;
    }
    __shared__ u16 tile[64][40];                      // pad: rows 80B
    int b  = blk / TBLK_PER_B;
    int n0 = (blk % TBLK_PER_B) * TCHUNK;
    const float* inb = inp + (size_t)b * CIN_ * N_;
    #pragma unroll
    for (int it = 0; it < 8; ++it) {
        int idx = it * 256 + tid;
        int c = idx >> 6, n = idx & 63;
        if (n0 + n < N_) tile[n][c] = f2bf(inb[(size_t)c * N_ + n0 + n]);
    }
    __syncthreads();
    int n = tid >> 2, seg = tid & 3;
    if (n0 + n < N_) {
        u16x8 v = *(const u16x8*)&tile[n][seg * 8];
        *(u16x8*)(xt + ((size_t)b * XT_ROWS + n0 + n) * CIN_ + seg * 8) = v;
    }
}

#define MFMA16(a, b, c) __builtin_amdgcn_mfma_f32_16x16x32_bf16((a), (b), (c), 0, 0, 0)

// Gather + MFMA GEMM, node-range 2-pass for L2 residency.
// Pass p gathers only idx in its 50k half (3.2MB slice per (batch,pass) < 4MB
// XCD L2). Masked lanes: branchless dummy in-slice address + zeroed B-frag.
// Full 64B rows (no line waste). Indices in LDS, acc in regs across passes.
// MFMA: A = W (o=l15), B = feats (node=l15), k = 32 channels of one neighbour.
__global__ __launch_bounds__(256, 4) void conv_kernel(
    const u16* __restrict__ xt, const u16* __restrict__ Wb,
    const int* __restrict__ nbr, const float* __restrict__ bias,
    float* __restrict__ out)
{
    __shared__ int idxl[4][4][16][28];                // 28,672 B
    int tid  = threadIdx.x;
    int bid  = blockIdx.x;
    int xcd  = bid & 7, slot = bid >> 3;              // slot 0..127
    int b    = xcd >> 2;                              // batch -> XCD half
    int wv   = tid >> 6, lane = tid & 63;
    int l15  = lane & 15, g = lane >> 4;
    int w    = (slot * 4 + (xcd & 3)) * 4 + wv;       // wave id in batch [0,2048)

    const int* nbb  = nbr + (size_t)b * N_ * K_;
    float*     outb = out + (size_t)b * COUT_ * N_;

    bool vj[4];
    #pragma unroll
    for (int j = 0; j < 4; ++j) vj[j] = (w + j * WPB) < TILES_PB;

    // ---- stage neighbour indices to LDS (coalesced reads, [node][k] layout) ----
    #pragma unroll
    for (int j = 0; j < 4; ++j) {
        if (!vj[j]) continue;
        const int* src = nbb + (size_t)(w + j * WPB) * (16 * K_);
        #pragma unroll
        for (int r = 0; r < 7; ++r) {
            int i = r * 64 + lane;
            if (i < 16 * K_) idxl[wv][j][i / K_][i % K_] = src[i];
        }
    }

    f32x4 acc[4][2];
    #pragma unroll
    for (int j = 0; j < 4; ++j) { acc[j][0] = 0.0f; acc[j][1] = 0.0f; }

    const u16* xg = xt + (size_t)b * XT_ROWS * CIN_ + (g << 3);  // +16B per g
    const u16* wg = Wb + l15 * 832 + (g << 3);

    __syncthreads();

    #pragma unroll
    for (int p = 0; p < 2; ++p) {                     // node-range pass
        const uint32_t dummy = p ? MID_ : 0;          // in-slice hot row for masked lanes
        #pragma unroll
        for (int k = 0; k < K_; ++k) {
            bf16x8 a0 = *(const bf16x8*)(wg + k * 32);            // o = l15
            bf16x8 a1 = *(const bf16x8*)(wg + 16 * 832 + k * 32); // o = l15+16
            #pragma unroll
            for (int j = 0; j < 4; ++j) {
                if (!vj[j]) continue;
                int idx = idxl[wv][j][l15][k];
                bool inr = (idx < MID_) == (p == 0);
                uint32_t ia = inr ? (uint32_t)idx : dummy;        // branchless
                bf16x8 f = *(const bf16x8*)(xg + ((size_t)ia << 5));
                f = inr ? f : (bf16x8)(short)0;                   // zero masked B-frag
                acc[j][0] = MFMA16(a0, f, acc[j][0]);
                acc[j][1] = MFMA16(a1, f, acc[j][1]);
            }
        }
        __syncthreads();                              // align block between passes
    }

    // ---- epilogue: D col = l15 -> node, D row = g*4+r -> o ----
    float bs0[4], bs1[4];
    #pragma unroll
    for (int r = 0; r < 4; ++r) {
        bs0[r] = bias[g * 4 + r];
        bs1[r] = bias[g * 4 + r + 16];
    }
    #pragma unroll
    for (int j = 0; j < 4; ++j) {
        if (!vj[j]) continue;
        int node = (w + j * WPB) * 16 + l15;
        #pragma unroll
        for (int r = 0; r < 4; ++r) {
            outb[(size_t)(g * 4 + r) * N_ + node]      = acc[j][0][r] + bs0[r];
            outb[(size_t)(g * 4 + r + 16) * N_ + node] = acc[j][1][r] + bs1[r];
        }
    }
}

extern "C" void kernel_launch(void* const* d_in, const int* in_sizes, int n_in,
                              void* d_out, int out_size, void* d_ws, size_t ws_size,
                              hipStream_t stream) {
    (void)in_sizes; (void)n_in; (void)out_size; (void)ws_size;
    const float* inp  = (const float*)d_in[0];
    const int*   nbr  = (const int*)d_in[1];
    const float* W    = (const float*)d_in[2];
    const float* bias = (const float*)d_in[3];
    const float* fill = (const float*)d_in[4];
    float* out = (float*)d_out;

    u16* xt = (u16*)d_ws;                              // [B][N+1][32] bf16
    u16* Wb = (u16*)((char*)d_ws + XT_BYTES);          // [32][832] bf16

    prep_kernel<<<PREP_GRID, 256, 0, stream>>>(inp, W, fill, xt, Wb);
    conv_kernel<<<CONV_GRID, 256, 0, stream>>>(xt, Wb, nbr, bias, out);
}

// Round 9
// 85.846 us; speedup vs baseline: 14.7492x; 14.7492x over previous
//
#include <hip/hip_runtime.h>
#include <stdint.h>

typedef uint16_t u16;
typedef __attribute__((ext_vector_type(8))) short    bf16x8;  // 8 bf16 (4 VGPRs)
typedef __attribute__((ext_vector_type(8))) uint16_t u16x8;
typedef __attribute__((ext_vector_type(4))) float    f32x4;

#define B_    2
#define N_    100000
#define K_    26
#define CIN_  32
#define COUT_ 32

#define XT_ROWS  (N_ + 1)
#define XT_BYTES ((size_t)B_ * XT_ROWS * CIN_ * 2)   // 12,800,128 bytes

// ---- prep kernel geometry (xt [B][N+1][32] bf16 64B rows, Wb [32][832] bf16) ----
#define TCHUNK      64
#define TBLK_PER_B  ((N_ + TCHUNK - 1) / TCHUNK)     // 1563
#define TBLKS       (B_ * TBLK_PER_B)                // 3126
#define WBLKS       13                               // 13 * 2048 = 26624 W elems
#define PREP_GRID   (TBLKS + 1 + WBLKS)

// ---- conv kernel geometry ----
// 512-thread blocks, grid 768 = EXACTLY 3 blocks/CU x 256 CU, all co-resident
// (LDS 53,760B x3 = 161,280 <= 163,840; VGPR capped 85 via launch_bounds).
// Per batch: 384 blocks x 8 waves = 3072 waves; 6250 tiles -> 2 (few 3) per wave.
#define CONV_GRID   768
#define WPB2        3072                             // waves per batch
#define TILES_PB    (N_ / 16)                        // 6250 exact (no node tail)
#define WPITCH      840                              // LDS W row pitch (2-way alias, free)

__device__ __forceinline__ u16 f2bf(float f) {
    union { float f; uint32_t u; } v; v.f = f;
    return (u16)((v.u + 0x7FFFu + ((v.u >> 16) & 1u)) >> 16);  // RNE
}

// Transpose inp [B][CIN][N] f32 -> xt [B][N+1][CIN] bf16 (64B rows),
// fill row at n==N, W -> Wb [32][832] bf16.
__global__ __launch_bounds__(256) void prep_kernel(
    const float* __restrict__ inp, const float* __restrict__ W,
    const float* __restrict__ fill, u16* __restrict__ xt, u16* __restrict__ Wb)
{
    int tid = threadIdx.x;
    int blk = blockIdx.x;
    if (blk >= TBLKS) {
        int job = blk - TBLKS;
        if (job == 0) {
            if (tid < B_ * CIN_) {
                int b = tid >> 5, c = tid & 31;
                xt[((size_t)b * XT_ROWS + N_) * CIN_ + c] = f2bf(fill[c]);
            }
        } else {
            int base = (job - 1) * 2048 + tid * 8;   // exact: 13*2048 = 26624
            const float4* src = (const float4*)(W + base);
            float4 x = src[0], y = src[1];
            u16x8 o;
            o[0] = f2bf(x.x); o[1] = f2bf(x.y); o[2] = f2bf(x.z); o[3] = f2bf(x.w);
            o[4] = f2bf(y.x); o[5] = f2bf(y.y); o[6] = f2bf(y.z); o[7] = f2bf(y.w);
            *(u16x8*)(Wb + base) = o;
        }
        return;
    }
    __shared__ u16 tile[64][40];                      // pad: rows 80B
    int b  = blk / TBLK_PER_B;
    int n0 = (blk % TBLK_PER_B) * TCHUNK;
    const float* inb = inp + (size_t)b * CIN_ * N_;
    #pragma unroll
    for (int it = 0; it < 8; ++it) {
        int idx = it * 256 + tid;
        int c = idx >> 6, n = idx & 63;
        if (n0 + n < N_) tile[n][c] = f2bf(inb[(size_t)c * N_ + n0 + n]);
    }
    __syncthreads();
    int n = tid >> 2, seg = tid & 3;
    if (n0 + n < N_) {
        u16x8 v = *(const u16x8*)&tile[n][seg * 8];
        *(u16x8*)(xt + ((size_t)b * XT_ROWS + n0 + n) * CIN_ + seg * 8) = v;
    }
}

#define MFMA16(a, b, c) __builtin_amdgcn_mfma_f32_16x16x32_bf16((a), (b), (c), 0, 0, 0)

// Gather + MFMA GEMM, 13-deep gather pipeline, W in LDS (vmcnt = gathers only).
// A = W (o = lane&15) from LDS, B = feats (node = lane&15) gathered 64B rows.
// Wave = one 16-node tile at a time, 2-3 tiles per wave.
// Batch -> XCD half: batch 0 on XCDs 0-3, batch 1 on XCDs 4-7.
__global__ __launch_bounds__(512, 6) void conv_kernel(
    const u16* __restrict__ xt, const u16* __restrict__ Wb,
    const int* __restrict__ nbr, const float* __restrict__ bias,
    float* __restrict__ out)
{
    __shared__ u16 Wl[COUT_ * WPITCH];                // 53,760 B
    int tid = threadIdx.x;
    // stage W into padded LDS rows: 3328 16B chunks / 512 threads
    for (int i = tid; i < 3328; i += 512) {
        int row = i / 104, c8 = i - row * 104;        // 104 chunks = 832 elems/row
        *(u16x8*)&Wl[row * WPITCH + c8 * 8] = *(const u16x8*)(Wb + row * 832 + c8 * 8);
    }
    __syncthreads();

    int bid  = blockIdx.x;
    int xcd  = bid & 7, slot = bid >> 3;              // slot 0..95
    int b    = xcd >> 2;                              // batch -> XCD half
    int wv   = tid >> 6, lane = tid & 63;
    int l15  = lane & 15, g = lane >> 4;
    int w    = (slot * 4 + (xcd & 3)) * 8 + wv;       // wave id in batch [0,3072)

    const u16* xg   = xt + (size_t)b * XT_ROWS * CIN_ + (g << 3);
    const int* nbb  = nbr + (size_t)b * N_ * K_;
    float*     outb = out + (size_t)b * COUT_ * N_;
    const u16* wl   = &Wl[l15 * WPITCH + (g << 3)];

    #pragma unroll 1
    for (int j = 0; j < 3; ++j) {                     // tiles w, w+3072, w+6144
        int t = w + j * WPB2;
        if (t >= TILES_PB) break;                     // wave-uniform
        const int* qp = nbb + ((size_t)t * 16 + l15) * K_;

        f32x4 acc0 = 0.0f, acc1 = 0.0f;

        // ---- issue 13 gathers (half 0) ----
        int q[13];
        #pragma unroll
        for (int k = 0; k < 13; ++k) q[k] = qp[k];
        bf16x8 f[13];
        #pragma unroll
        for (int k = 0; k < 13; ++k)
            f[k] = *(const bf16x8*)(xg + ((size_t)(uint32_t)q[k] << 5));
        __builtin_amdgcn_sched_barrier(0);            // pin issue block above consumers

        // ---- consume half 0, refill each slot with half-1 gather ----
        #pragma unroll
        for (int k = 0; k < 13; ++k) {
            bf16x8 a0 = *(const bf16x8*)(wl + k * 32);            // o = l15
            bf16x8 a1 = *(const bf16x8*)(wl + 16 * WPITCH + k * 32);
            int qn = qp[13 + k];                      // same nbr row, L1-hot
            acc0 = MFMA16(a0, f[k], acc0);
            acc1 = MFMA16(a1, f[k], acc1);
            f[k] = *(const bf16x8*)(xg + ((size_t)(uint32_t)qn << 5));
        }
        __builtin_amdgcn_sched_barrier(0);

        // ---- consume half 1 ----
        #pragma unroll
        for (int k = 0; k < 13; ++k) {
            bf16x8 a0 = *(const bf16x8*)(wl + (13 + k) * 32);
            bf16x8 a1 = *(const bf16x8*)(wl + 16 * WPITCH + (13 + k) * 32);
            acc0 = MFMA16(a0, f[k], acc0);
            acc1 = MFMA16(a1, f[k], acc1);
        }

        // ---- epilogue: D col = l15 -> node, D row = g*4+r -> o ----
        int node = t * 16 + l15;
        #pragma unroll
        for (int r = 0; r < 4; ++r) {
            outb[(size_t)(g * 4 + r) * N_ + node]      = acc0[r] + bias[g * 4 + r];
            outb[(size_t)(g * 4 + r + 16) * N_ + node] = acc1[r] + bias[g * 4 + r + 16];
        }
    }
}

extern "C" void kernel_launch(void* const* d_in, const int* in_sizes, int n_in,
                              void* d_out, int out_size, void* d_ws, size_t ws_size,
                              hipStream_t stream) {
    (void)in_sizes; (void)n_in; (void)out_size; (void)ws_size;
    const float* inp  = (const float*)d_in[0];
    const int*   nbr  = (const int*)d_in[1];
    const float* W    = (const float*)d_in[2];
    const float* bias = (const float*)d_in[3];
    const float* fill = (const float*)d_in[4];
    float* out = (float*)d_out;

    u16* xt = (u16*)d_ws;                              // [B][N+1][32] bf16
    u16* Wb = (u16*)((char*)d_ws + XT_BYTES);          // [32][832] bf16

    prep_kernel<<<PREP_GRID, 256, 0, stream>>>(inp, W, fill, xt, Wb);
    conv_kernel<<<CONV_GRID, 512, 0, stream>>>(xt, Wb, nbr, bias, out);
}